// Round 1
// baseline (62.670 us; speedup 1.0000x reference)
//
#include <hip/hip_runtime.h>

// Path signature, depth 4, for path (N=64, L=512, C=8) float32.
// Output: per batch, concat of levels 1..4 -> 8 + 64 + 512 + 4096 = 4680 floats.
//
// Strategy: the truncated-tensor-algebra product is associative, so
//   Sig = exp(z_1) (x) exp(z_2) (x) ... (x) exp(z_511)
// is computed as K chunks in parallel (phase 1, sequential Chen steps within a
// chunk), then combined left-to-right per batch element (phase 2).

#define NBATCH 64
#define LPATH  512
#define CDIM   8
#define SIG_SIZE 4680      // 8 + 64 + 512 + 4096
#define OFF2 8
#define OFF3 72
#define OFF4 584           // start of level 4; also size of levels 1..3

// ---------------------------------------------------------------------------
// Phase 1: signature of one chunk of increments, starting from identity.
// One workgroup (256 threads) per (batch, chunk). blockIdx.x = n*K + chunk.
// Level-4 state: 16 floats per thread in registers (thread t owns flat
// elements t*16 .. t*16+15). Levels 1..3: double-buffered LDS (584 floats).
// One __syncthreads per step.
// ---------------------------------------------------------------------------
__global__ __launch_bounds__(256) void sig_chunk_kernel(
    const float* __restrict__ path, float* __restrict__ dest,
    int K, int spc)
{
    const int tid   = threadIdx.x;
    const int n     = blockIdx.x / K;
    const int t0    = (blockIdx.x % K) * spc;
    int t1 = t0 + spc; if (t1 > LPATH - 1) t1 = LPATH - 1;
    const int nsteps = (t1 > t0) ? (t1 - t0) : 0;

    __shared__ float P[LPATH * CDIM];  // staged path rows for this chunk
    __shared__ float S[2][OFF4];       // levels 1..3, double buffered

    // stage path rows t0 .. t0+nsteps (nsteps+1 rows)
    const int nelems = (nsteps + 1) * CDIM;
    const float* psrc = path + (size_t)n * LPATH * CDIM + (size_t)t0 * CDIM;
    for (int i = tid; i < nelems; i += 256) P[i] = psrc[i];
    for (int i = tid; i < OFF4;   i += 256) S[0][i] = 0.0f;

    float s4[16];
    #pragma unroll
    for (int j = 0; j < 16; ++j) s4[j] = 0.0f;

    // this thread's 16 level-4 elements: e = tid*16 + cc*8 + d,
    // (a,b,c,d) with c = c0+cc
    const int a  = tid >> 5;
    const int b  = (tid >> 2) & 7;
    const int c0 = (tid & 3) * 2;
    // this thread's 2 owned level-3 elements: f = 2*tid, 2*tid+1 = (b',c',d')
    const int f0  = 2 * tid;
    const int s3b = f0 >> 6;
    const int s3c = (f0 >> 3) & 7;
    const int s3d = f0 & 7;        // even; second element is s3d+1, same (b',c')

    __syncthreads();

    float pr[8];
    #pragma unroll
    for (int d = 0; d < 8; ++d) pr[d] = P[d];

    int p = 0;
    for (int s = 0; s < nsteps; ++s) {
        float z[8];
        #pragma unroll
        for (int d = 0; d < 8; ++d) {
            float nx = P[(s + 1) * 8 + d];
            z[d] = nx - pr[d];
            pr[d] = nx;
        }

        const float* Sp = S[p];

        // ---- level 4 (registers) ----
        // S4[abcd] += z[d] * ( z[c] * (z[a]z[b]/24 + S1[a]z[b]/6 + S2[ab]/2) + S3[abc] )
        float s1a    = Sp[a];
        float s2ab   = Sp[OFF2 + a * 8 + b];
        float s3abc0 = Sp[OFF3 + (a * 8 + b) * 8 + c0];
        float s3abc1 = Sp[OFF3 + (a * 8 + b) * 8 + c0 + 1];
        float B  = z[b] * (z[a] * (1.0f / 24.0f) + s1a * (1.0f / 6.0f)) + s2ab * 0.5f;
        float A0 = B * z[c0]     + s3abc0;
        float A1 = B * z[c0 + 1] + s3abc1;
        #pragma unroll
        for (int d = 0; d < 8; ++d) {
            s4[d]     += A0 * z[d];
            s4[8 + d] += A1 * z[d];
        }

        // ---- level 3 (2 owned elements) ----
        // S3[b'c'd'] += z[d'] * ( z[b']z[c']/6 + S1[b']z[c']/2 + S2[b'c'] )
        float s1b  = Sp[s3b];
        float s2bc = Sp[OFF2 + s3b * 8 + s3c];
        float G = z[s3c] * (z[s3b] * (1.0f / 6.0f) + s1b * 0.5f) + s2bc;
        float n3_0 = Sp[OFF3 + f0]     + z[s3d]     * G;
        float n3_1 = Sp[OFF3 + f0 + 1] + z[s3d + 1] * G;

        // ---- level 2 / level 1 ----
        float n2 = 0.0f, n1 = 0.0f;
        if (tid < 64) {
            int c2 = tid >> 3, d2 = tid & 7;
            n2 = Sp[OFF2 + tid] + z[d2] * (Sp[c2] + z[c2] * 0.5f);
        }
        if (tid < 8) n1 = Sp[tid] + z[tid];

        float* Sq = S[p ^ 1];
        Sq[OFF3 + f0]     = n3_0;
        Sq[OFF3 + f0 + 1] = n3_1;
        if (tid < 64) Sq[OFF2 + tid] = n2;
        if (tid < 8)  Sq[tid] = n1;
        __syncthreads();
        p ^= 1;
    }

    // write chunk signature (ws slot, or d_out directly when K==1)
    float* dst = dest + (size_t)blockIdx.x * SIG_SIZE;
    for (int i = tid; i < OFF4; i += 256) dst[i] = S[p][i];
    #pragma unroll
    for (int j = 0; j < 16; ++j) dst[OFF4 + tid * 16 + j] = s4[j];
}

// ---------------------------------------------------------------------------
// Phase 2: per batch element, left-to-right product of the K chunk signatures.
// R_k = sum_{j=0..k} A_{k-j} (x) B_j  (A = accumulated prefix, B = next chunk)
// One workgroup (256 threads) per batch element.
// ---------------------------------------------------------------------------
__global__ __launch_bounds__(256) void sig_combine_kernel(
    const float* __restrict__ ws, float* __restrict__ out, int K)
{
    const int tid = threadIdx.x;
    const int n   = blockIdx.x;

    __shared__ float A[2][OFF4];
    __shared__ float Bs[OFF4];

    const float* base = ws + (size_t)n * K * SIG_SIZE;

    for (int i = tid; i < OFF4; i += 256) A[0][i] = base[i];
    float a4[16];
    #pragma unroll
    for (int j = 0; j < 16; ++j) a4[j] = base[OFF4 + tid * 16 + j];

    const int a  = tid >> 5;
    const int b  = (tid >> 2) & 7;
    const int c0 = (tid & 3) * 2;
    const int f0  = 2 * tid;
    const int s3b = f0 >> 6;
    const int s3c = (f0 >> 3) & 7;
    const int s3d = f0 & 7;

    int p = 0;
    for (int m = 1; m < K; ++m) {
        const float* bsrc = base + (size_t)m * SIG_SIZE;
        for (int i = tid; i < OFF4; i += 256) Bs[i] = bsrc[i];
        __syncthreads();

        const float* Ap = A[p];

        // ---- level 4 ----
        float a1   = Ap[a];
        float a2   = Ap[OFF2 + a * 8 + b];
        float a3c0 = Ap[OFF3 + (a * 8 + b) * 8 + c0];
        float a3c1 = Ap[OFF3 + (a * 8 + b) * 8 + c0 + 1];
        #pragma unroll
        for (int j = 0; j < 16; ++j) {
            int c = c0 + (j >> 3);
            int d = j & 7;
            float a3 = (j < 8) ? a3c0 : a3c1;
            float v = a4[j] + bsrc[OFF4 + tid * 16 + j];   // A4 + B4
            v += a1 * Bs[OFF3 + (b * 8 + c) * 8 + d];      // A1 (x) B3
            v += a2 * Bs[OFF2 + c * 8 + d];                // A2 (x) B2
            v += a3 * Bs[d];                               // A3 (x) B1
            a4[j] = v;
        }

        // ---- level 3 ----
        float b1   = Ap[s3b];
        float a2bc = Ap[OFF2 + s3b * 8 + s3c];
        float n3_0 = Ap[OFF3 + f0]     + Bs[OFF3 + f0]
                   + b1 * Bs[OFF2 + s3c * 8 + s3d]     + a2bc * Bs[s3d];
        float n3_1 = Ap[OFF3 + f0 + 1] + Bs[OFF3 + f0 + 1]
                   + b1 * Bs[OFF2 + s3c * 8 + s3d + 1] + a2bc * Bs[s3d + 1];

        // ---- level 2 / 1 ----
        float n2 = 0.0f, n1 = 0.0f;
        if (tid < 64) {
            int c2 = tid >> 3, d2 = tid & 7;
            n2 = Ap[OFF2 + tid] + Bs[OFF2 + tid] + Ap[c2] * Bs[d2];
        }
        if (tid < 8) n1 = Ap[tid] + Bs[tid];

        float* Aq = A[p ^ 1];
        Aq[OFF3 + f0]     = n3_0;
        Aq[OFF3 + f0 + 1] = n3_1;
        if (tid < 64) Aq[OFF2 + tid] = n2;
        if (tid < 8)  Aq[tid] = n1;
        __syncthreads();
        p ^= 1;
    }

    float* dst = out + (size_t)n * SIG_SIZE;
    for (int i = tid; i < OFF4; i += 256) dst[i] = A[p][i];
    #pragma unroll
    for (int j = 0; j < 16; ++j) dst[OFF4 + tid * 16 + j] = a4[j];
}

extern "C" void kernel_launch(void* const* d_in, const int* in_sizes, int n_in,
                              void* d_out, int out_size, void* d_ws, size_t ws_size,
                              hipStream_t stream) {
    const float* path = (const float*)d_in[0];
    float* out = (float*)d_out;
    float* ws  = (float*)d_ws;

    int K = 16;
    while (K > 1 && (size_t)NBATCH * K * SIG_SIZE * sizeof(float) > ws_size) K >>= 1;
    const int spc = (LPATH - 1 + K - 1) / K;   // increments per chunk

    if (K == 1) {
        sig_chunk_kernel<<<NBATCH, 256, 0, stream>>>(path, out, 1, spc);
    } else {
        sig_chunk_kernel<<<NBATCH * K, 256, 0, stream>>>(path, ws, K, spc);
        sig_combine_kernel<<<NBATCH, 256, 0, stream>>>(ws, out, K);
    }
}